// Round 6
// baseline (1548.805 us; speedup 1.0000x reference)
//
#include <hip/hip_runtime.h>
#include <cstdint>
#include <cstddef>

#define B_   4
#define S_   2048
#define D_   2048
#define NH_  16
#define NKV_ 4
#define HD_  128

typedef __attribute__((ext_vector_type(8))) short short8;
typedef __attribute__((ext_vector_type(4))) float f32x4;

// ---------------------------------------------------------------------------
// fp32 -> (bf16_hi, bf16_lo) split helpers (RNE)
// ---------------------------------------------------------------------------
__device__ __forceinline__ unsigned short f2bf(float f) {
    union { float f; unsigned u; } v{f};
    unsigned r = v.u + 0x7FFF + ((v.u >> 16) & 1);
    return (unsigned short)(r >> 16);
}
__device__ __forceinline__ float bf2f(unsigned short h) {
    union { unsigned u; float f; } v{(unsigned)h << 16};
    return v.f;
}
__device__ __forceinline__ void split1(float f, unsigned short& h, unsigned short& l) {
    h = f2bf(f);
    l = f2bf(f - bf2f(h));
}
// 8 packed u32 (hi|lo<<16) -> two bf16x8 fragments
__device__ __forceinline__ void unpack8(const unsigned* w, short8& hi, short8& lo) {
    unsigned h[4], l[4];
#pragma unroll
    for (int i = 0; i < 4; ++i) {
        h[i] = (w[2*i] & 0xFFFFu) | (w[2*i+1] << 16);
        l[i] = (w[2*i] >> 16) | (w[2*i+1] & 0xFFFF0000u);
    }
    hi = *(short8*)h; lo = *(short8*)l;
}

// src fp32 [n] -> hi/lo bf16 [n]. n must be a multiple of 1024.
__global__ __launch_bounds__(256) void split_bf16_k(
    const float* __restrict__ src, ushort* __restrict__ hi, ushort* __restrict__ lo)
{
    size_t i = ((size_t)blockIdx.x * 256 + threadIdx.x) * 4;
    float4 f = *(const float4*)&src[i];
    ushort4 h, l;
    split1(f.x, h.x, l.x); split1(f.y, h.y, l.y);
    split1(f.z, h.z, l.z); split1(f.w, h.w, l.w);
    *(ushort4*)&hi[i] = h;
    *(ushort4*)&lo[i] = l;
}

// ---------------------------------------------------------------------------
// Split-bf16 MFMA GEMM (round-3 verified form):
// C[M,N] = (Ah+Al)[M,K] @ (Bh+Bl)[N,K]^T + bias  (drops lo*lo)
// ---------------------------------------------------------------------------
__global__ __launch_bounds__(256) void gemm_mfma_split(
    const ushort* __restrict__ Ah, const ushort* __restrict__ Al,
    const ushort* __restrict__ Bh, const ushort* __restrict__ Bl,
    const float* __restrict__ bias, float* __restrict__ C,
    int M, int N, int K)
{
    __shared__ ushort sA[2][128 * 32];   // [0]=hi [1]=lo, row-major [128][32]
    __shared__ ushort sB[2][128 * 32];

    const int tid  = threadIdx.x;
    const int wave = tid >> 6;
    const int lane = tid & 63;
    const int bm = blockIdx.y * 128;
    const int bn = blockIdx.x * 128;
    const int wm = (wave & 1) * 64;
    const int wn = (wave >> 1) * 64;

    f32x4 acc[4][4];
#pragma unroll
    for (int mt = 0; mt < 4; ++mt)
#pragma unroll
        for (int nt = 0; nt < 4; ++nt) acc[mt][nt] = 0.f;

    const ushort* gbase = (wave == 0) ? Ah : (wave == 1) ? Al : (wave == 2) ? Bh : Bl;
    ushort* sbase = (wave == 0) ? sA[0] : (wave == 1) ? sA[1] : (wave == 2) ? sB[0] : sB[1];
    const int rb   = (wave < 2) ? bm : bn;
    const int lrow = lane >> 2;          // 0..15
    const int lcol = (lane & 3) * 8;     // element offset in k

    const int koff = (lane >> 4) * 8;
    const int rsel = lane & 15;

    for (int k0 = 0; k0 < K; k0 += 32) {
        __syncthreads();
        const ushort* g0 = gbase + (size_t)(rb + lrow) * K + k0 + lcol;
#pragma unroll
        for (int i = 0; i < 8; ++i) {
            __builtin_amdgcn_global_load_lds(
                (const __attribute__((address_space(1))) unsigned int*)(g0 + (size_t)i * 16 * K),
                (__attribute__((address_space(3))) unsigned int*)(sbase + i * 512),
                16, 0, 0);
        }
        __syncthreads();

        short8 a_h[4], a_l[4], b_h[4], b_l[4];
#pragma unroll
        for (int t = 0; t < 4; ++t) {
            a_h[t] = *(const short8*)&sA[0][(wm + t * 16 + rsel) * 32 + koff];
            a_l[t] = *(const short8*)&sA[1][(wm + t * 16 + rsel) * 32 + koff];
            b_h[t] = *(const short8*)&sB[0][(wn + t * 16 + rsel) * 32 + koff];
            b_l[t] = *(const short8*)&sB[1][(wn + t * 16 + rsel) * 32 + koff];
        }
#pragma unroll
        for (int mt = 0; mt < 4; ++mt)
#pragma unroll
            for (int nt = 0; nt < 4; ++nt) {
                acc[mt][nt] = __builtin_amdgcn_mfma_f32_16x16x32_bf16(a_h[mt], b_h[nt], acc[mt][nt], 0, 0, 0);
                acc[mt][nt] = __builtin_amdgcn_mfma_f32_16x16x32_bf16(a_h[mt], b_l[nt], acc[mt][nt], 0, 0, 0);
                acc[mt][nt] = __builtin_amdgcn_mfma_f32_16x16x32_bf16(a_l[mt], b_h[nt], acc[mt][nt], 0, 0, 0);
            }
    }

    const int crow0 = bm + wm + (lane >> 4) * 4;
    const int ccol0 = bn + wn + (lane & 15);
#pragma unroll
    for (int nt = 0; nt < 4; ++nt) {
        float bb = bias ? bias[ccol0 + nt * 16] : 0.f;
#pragma unroll
        for (int mt = 0; mt < 4; ++mt)
#pragma unroll
            for (int r = 0; r < 4; ++r)
                C[(size_t)(crow0 + mt * 16 + r) * N + ccol0 + nt * 16] = acc[mt][nt][r] + bb;
    }
}

// ---------------------------------------------------------------------------
// In-place RoPE (+scale) and fp32 -> interleaved hi/lo bf16 split.
// Row r of 128 fp32 becomes 128 hi ushorts | 128 lo ushorts (same 512 bytes).
// ---------------------------------------------------------------------------
__global__ __launch_bounds__(256) void rope_split_kernel(
    float* __restrict__ t, int H, float scale, int do_rope)
{
    const int tid = threadIdx.x;
    const int rid = blockIdx.x * 2 + (tid >> 7);
    const int d   = tid & 127;
    size_t fbase = (size_t)rid * 128;
    float val;
    if (do_rope) {
        const int s = (rid / H) & (S_ - 1);
        const int j = d & 63;
        float inv  = 1.0f / powf(1.0e6f, (float)j * (1.0f / 64.0f));
        float fr = (float)s * inv;
        float sn, cs; sincosf(fr, &sn, &cs);
        float x0 = t[fbase + d];
        float xp = t[fbase + (d ^ 64)];
        float rot = (d < 64) ? -xp : xp;
        val = fmaf(x0, cs, rot * sn) * scale;
    } else {
        val = t[fbase + d] * scale;
    }
    __syncthreads();               // all fp32 reads of these 2 rows done
    unsigned short h, l; split1(val, h, l);
    ushort* us = (ushort*)t;
    us[(size_t)rid * 256 + d]       = h;
    us[(size_t)rid * 256 + 128 + d] = l;
}

// ---------------------------------------------------------------------------
// MFMA causal flash attention, GQA, split-bf16 precision.
// Qsp: interleaved hi/lo Q rows [B,S,NH]x(128h|128l) (read-only here).
// Ksp/Vsp: interleaved hi/lo K/V rows [B,S,NKV]x(128h|128l).
// ctx_h/ctx_l: PLANAR outputs, [B*S][2048] ushorts, feature = h*128+d.
// Block: 4 waves x 32 q-rows (BM=128); KV tile BN=32.
//
// Round 5 structure:
//  * K is NEVER staged in LDS. Each lane loads its A-fragment directly from
//    global (L2-resident: a 16KB K tile is reused by 64 blocks): lane
//    (l15,quad), half-tile mf reads global kv row 8*(l15>>2)+4*mf+(l15&3),
//    k-slice ks*32+quad*8. This choice of row assignment makes the QK^T
//    C-layout leave P at kv = quad*8 + mf*4 + r — exactly the contiguous
//    8-element k-slice the PV A-fragment needs (round-3 verified mapping).
//    Halves per-block-tile LDS read traffic (the round-4 post-mortem cost:
//    4 waves x 32KB ds_read_b128 per tile ~ 1.5k cy of shared LDS pipe).
//  * Only V lives in LDS (transposed+packed), double-buffered, ONE barrier
//    per tile: prefetch V(t+1) to regs before compute, ds_write after PV.
//  * P never touches LDS (register pack, round-2 trick).
//
// __launch_bounds__(256, 2): (256,4) forces VGPR->64 and spills (round 1).
// ---------------------------------------------------------------------------
__global__ __launch_bounds__(256, 2) void flash_attn_mfma(
    const ushort* __restrict__ Qsp, const ushort* __restrict__ Ksp,
    const ushort* __restrict__ Vsp, ushort* __restrict__ ctx_h,
    ushort* __restrict__ ctx_l)
{
    __shared__ __align__(16) unsigned Vt[2][128][36];  // [feat][kv] hi|lo<<16

    const int tid  = threadIdx.x;
    const int wave = tid >> 6;
    const int lane = tid & 63;
    const int l15  = lane & 15;
    const int quad = lane >> 4;
    const int q0   = (gridDim.x - 1 - blockIdx.x) * 128;   // heavy tiles first
    const int h    = blockIdx.y;
    const int b    = blockIdx.z;
    const int kvh  = h >> 2;
    const int wq0  = q0 + wave * 32;

    // V staging geometry (constant across tiles)
    const int vrow = tid & 31;          // kv row this thread loads
    const int vfs  = tid >> 5;          // feature-slice (x16), 0..7
    const size_t kvstride = (size_t)NKV_ * 256;   // ushorts per kv row
    const ushort* vbase = Vsp + ((size_t)b * S_ * NKV_ + kvh) * 256 + vfs * 16;

    // K direct-load pointers (per lane, advanced by 32 rows per tile)
    const int krow0 = 8 * (l15 >> 2) + (l15 & 3);          // mf=0 row
    const ushort* pK0 = Ksp + (((size_t)b * S_ + krow0)     * NKV_ + kvh) * 256 + quad * 8;
    const ushort* pK1 = Ksp + (((size_t)b * S_ + krow0 + 4) * NKV_ + kvh) * 256 + quad * 8;

    // V prefetch registers
    uint4 vstg[4];   // [0]=hf0 hi [1]=hf0 lo [2]=hf1 hi [3]=hf1 lo

#define LOADV(K0)                                                               \
    {                                                                           \
        const ushort* vs = vbase + (size_t)((K0) + vrow) * kvstride;            \
        vstg[0] = *(const uint4*)(vs);                                          \
        vstg[1] = *(const uint4*)(vs + 128);                                    \
        vstg[2] = *(const uint4*)(vs + 8);                                      \
        vstg[3] = *(const uint4*)(vs + 136);                                    \
    }

#define STOREV(NB)                                                              \
    {                                                                           \
        _Pragma("unroll")                                                       \
        for (int hf = 0; hf < 2; ++hf) {                                        \
            const ushort* hp = (const ushort*)&vstg[hf * 2];                    \
            const ushort* lp = (const ushort*)&vstg[hf * 2 + 1];                \
            _Pragma("unroll")                                                   \
            for (int i = 0; i < 8; ++i)                                         \
                Vt[NB][vfs * 16 + hf * 8 + i][vrow] =                           \
                    (unsigned)hp[i] | ((unsigned)lp[i] << 16);                  \
        }                                                                       \
    }

    // ---- Q fragments (B-operand) into registers: [nf][ks][plane] ----
    short8 qf[2][4][2];
#pragma unroll
    for (int nf = 0; nf < 2; ++nf)
#pragma unroll
        for (int ks = 0; ks < 4; ++ks) {
            size_t base = (((size_t)b * S_ + wq0 + nf * 16 + l15) * NH_ + h) * 256
                        + ks * 32 + quad * 8;
            qf[nf][ks][0] = *(const short8*)&Qsp[base];
            qf[nf][ks][1] = *(const short8*)&Qsp[base + 128];
        }

    f32x4 O[2][8];
#pragma unroll
    for (int mf = 0; mf < 2; ++mf)
#pragma unroll
        for (int nf = 0; nf < 8; ++nf) O[mf][nf] = 0.f;
    float m_[2] = {-3.0e38f, -3.0e38f};
    float l_[2] = {0.f, 0.f};

    const int ntiles = q0 / 32 + 4;

    // ---- prologue: stage V tile 0 into buffer 0 ----
    LOADV(0);
    STOREV(0);
    __syncthreads();

    for (int t = 0; t < ntiles; ++t) {
        const int cur = t & 1;
        const int k0 = t * 32;
        const bool pf = (t + 1 < ntiles);

        // issue tile t+1's V loads now — latency hides under compute(t)
        if (pf) LOADV(k0 + 32);

        // ---- S^T = K . Q^T, K direct from global (L2) ----
        f32x4 st[2][2];                        // [nf(q)][mf(kv half-tile)]
#pragma unroll
        for (int nf = 0; nf < 2; ++nf)
#pragma unroll
            for (int mf = 0; mf < 2; ++mf) st[nf][mf] = 0.f;
#pragma unroll
        for (int ks = 0; ks < 4; ++ks) {
            short8 kh0 = *(const short8*)(pK0 + ks * 32);
            short8 kl0 = *(const short8*)(pK0 + ks * 32 + 128);
            short8 kh1 = *(const short8*)(pK1 + ks * 32);
            short8 kl1 = *(const short8*)(pK1 + ks * 32 + 128);
#pragma unroll
            for (int nf = 0; nf < 2; ++nf) {
                st[nf][0] = __builtin_amdgcn_mfma_f32_16x16x32_bf16(kh0, qf[nf][ks][0], st[nf][0], 0, 0, 0);
                st[nf][0] = __builtin_amdgcn_mfma_f32_16x16x32_bf16(kh0, qf[nf][ks][1], st[nf][0], 0, 0, 0);
                st[nf][0] = __builtin_amdgcn_mfma_f32_16x16x32_bf16(kl0, qf[nf][ks][0], st[nf][0], 0, 0, 0);
                st[nf][1] = __builtin_amdgcn_mfma_f32_16x16x32_bf16(kh1, qf[nf][ks][0], st[nf][1], 0, 0, 0);
                st[nf][1] = __builtin_amdgcn_mfma_f32_16x16x32_bf16(kh1, qf[nf][ks][1], st[nf][1], 0, 0, 0);
                st[nf][1] = __builtin_amdgcn_mfma_f32_16x16x32_bf16(kl1, qf[nf][ks][0], st[nf][1], 0, 0, 0);
            }
        }
        pK0 += 32 * kvstride;
        pK1 += 32 * kvstride;

        // ---- causal mask (actual kv = k0 + quad*8 + mf*4 + r) ----
        if (k0 + 31 > wq0) {
#pragma unroll
            for (int nf = 0; nf < 2; ++nf)
#pragma unroll
                for (int mf = 0; mf < 2; ++mf)
#pragma unroll
                    for (int r = 0; r < 4; ++r) {
                        int kg = k0 + quad * 8 + mf * 4 + r;
                        int qg = wq0 + nf * 16 + l15;
                        if (kg > qg) st[nf][mf][r] = -3.0e38f;
                    }
        }

        // ---- online softmax (per q column; reduce in-lane + across quads) ----
        float alp[2];
#pragma unroll
        for (int nf = 0; nf < 2; ++nf) {
            float rm = -3.0e38f;
#pragma unroll
            for (int mf = 0; mf < 2; ++mf)
#pragma unroll
                for (int r = 0; r < 4; ++r) rm = fmaxf(rm, st[nf][mf][r]);
            rm = fmaxf(rm, __shfl_xor(rm, 16));
            rm = fmaxf(rm, __shfl_xor(rm, 32));
            float mn = fmaxf(m_[nf], rm);
            float a  = __expf(m_[nf] - mn);
            float rs = 0.f;
#pragma unroll
            for (int mf = 0; mf < 2; ++mf)
#pragma unroll
                for (int r = 0; r < 4; ++r) {
                    float p = __expf(st[nf][mf][r] - mn);
                    st[nf][mf][r] = p;
                    rs += p;
                }
            rs += __shfl_xor(rs, 16);
            rs += __shfl_xor(rs, 32);
            l_[nf] = l_[nf] * a + rs;
            m_[nf] = mn;
            alp[nf] = a;
        }

        // ---- rescale O (alpha fetched from owner lane of each q row) ----
#pragma unroll
        for (int omf = 0; omf < 2; ++omf)
#pragma unroll
            for (int r = 0; r < 4; ++r) {
                float av = __shfl(alp[omf], (lane & 48) | (quad * 4 + r));
#pragma unroll
                for (int nf = 0; nf < 8; ++nf) O[omf][nf][r] *= av;
            }

        // ---- P stays in registers: lane already holds kv = quad*8+0..7 ----
        short8 ph[2], pl[2];
#pragma unroll
        for (int omf = 0; omf < 2; ++omf) {
            unsigned hu[4], lu[4];
#pragma unroll
            for (int mf = 0; mf < 2; ++mf)
#pragma unroll
                for (int pr = 0; pr < 2; ++pr) {
                    unsigned short ah, al, bh, bl;
                    split1(st[omf][mf][pr * 2],     ah, al);
                    split1(st[omf][mf][pr * 2 + 1], bh, bl);
                    hu[mf * 2 + pr] = (unsigned)ah | ((unsigned)bh << 16);
                    lu[mf * 2 + pr] = (unsigned)al | ((unsigned)bl << 16);
                }
            ph[omf] = *(short8*)hu;
            pl[omf] = *(short8*)lu;
        }

        // ---- O += P . V ----
#pragma unroll
        for (int vnf = 0; vnf < 8; ++vnf) {
            const unsigned* vw = &Vt[cur][vnf * 16 + l15][quad * 8];
            unsigned w[8];
            *(uint4*)w       = *(const uint4*)vw;
            *(uint4*)(w + 4) = *(const uint4*)(vw + 4);
            short8 vh, vl;
            unpack8(w, vh, vl);
#pragma unroll
            for (int omf = 0; omf < 2; ++omf) {
                O[omf][vnf] = __builtin_amdgcn_mfma_f32_16x16x32_bf16(ph[omf], vh, O[omf][vnf], 0, 0, 0);
                O[omf][vnf] = __builtin_amdgcn_mfma_f32_16x16x32_bf16(ph[omf], vl, O[omf][vnf], 0, 0, 0);
                O[omf][vnf] = __builtin_amdgcn_mfma_f32_16x16x32_bf16(pl[omf], vh, O[omf][vnf], 0, 0, 0);
            }
        }

        // ---- write prefetched V tile t+1 into the other buffer ----
        if (pf) STOREV(cur ^ 1);
        __syncthreads();
    }

#undef LOADV
#undef STOREV

    // ---- epilogue: normalize, split, store planar ctx ----
    float li[2] = {1.f / l_[0], 1.f / l_[1]};
#pragma unroll
    for (int omf = 0; omf < 2; ++omf)
#pragma unroll
        for (int r = 0; r < 4; ++r) {
            float il = __shfl(li[omf], (lane & 48) | (quad * 4 + r));
            int qrow = wq0 + omf * 16 + quad * 4 + r;
            size_t rowb = ((size_t)b * S_ + qrow) * (size_t)D_ + h * HD_;
#pragma unroll
            for (int nf = 0; nf < 8; ++nf) {
                float val = O[omf][nf][r] * il;
                unsigned short hh, ll; split1(val, hh, ll);
                int feat = nf * 16 + l15;
                ctx_h[rowb + feat] = hh;
                ctx_l[rowb + feat] = ll;
            }
        }
}

// ---------------------------------------------------------------------------
extern "C" void kernel_launch(void* const* d_in, const int* in_sizes, int n_in,
                              void* d_out, int out_size, void* d_ws, size_t ws_size,
                              hipStream_t stream)
{
    const float* x    = (const float*)d_in[0];
    const float* wq_w = (const float*)d_in[1];
    const float* wq_b = (const float*)d_in[2];
    const float* wk_w = (const float*)d_in[3];
    const float* wk_b = (const float*)d_in[4];
    const float* wv_w = (const float*)d_in[5];
    const float* wv_b = (const float*)d_in[6];
    const float* wo_w = (const float*)d_in[7];
    float* out = (float*)d_out;

    const int M = B_ * S_;                        // 8192
    const size_t NX   = (size_t)M * D_;           // 16,777,216
    const size_t NKVE = (size_t)M * NKV_ * HD_;   // 4,194,304
    const size_t NWQ  = (size_t)D_ * D_;
    const size_t NWK  = (size_t)(NKV_ * HD_) * D_;

    // workspace layout
    float*  q   = (float*)d_ws;          // becomes interleaved split Q
    float*  k   = q + NX;                // becomes interleaved split K
    float*  v   = k + NKVE;              // becomes interleaved split V
    ushort* xh  = (ushort*)(v + NKVE);   // x hi split; later ctx_h (planar)
    ushort* xl  = xh + NX;               // x lo split; later ctx_l (planar)
    ushort* wqh = xl + NX;
    ushort* wql = wqh + NWQ;
    ushort* wkh = wql + NWQ;
    ushort* wkl = wkh + NWK;
    ushort* wvh = wkl + NWK;
    ushort* wvl = wvh + NWK;
    ushort* woh = wvl + NWK;
    ushort* wol = woh + NWQ;

    // 1) fp32 -> bf16 hi/lo splits
    split_bf16_k<<<NX  / 1024, 256, 0, stream>>>(x,    xh,  xl);
    split_bf16_k<<<NWQ / 1024, 256, 0, stream>>>(wq_w, wqh, wql);
    split_bf16_k<<<NWK / 1024, 256, 0, stream>>>(wk_w, wkh, wkl);
    split_bf16_k<<<NWK / 1024, 256, 0, stream>>>(wv_w, wvh, wvl);
    split_bf16_k<<<NWQ / 1024, 256, 0, stream>>>(wo_w, woh, wol);

    // 2) QKV projections (fp32 outputs)
    gemm_mfma_split<<<dim3(D_/128,         M/128), 256, 0, stream>>>(xh, xl, wqh, wql, wq_b, q, M, D_,       D_);
    gemm_mfma_split<<<dim3((NKV_*HD_)/128, M/128), 256, 0, stream>>>(xh, xl, wkh, wkl, wk_b, k, M, NKV_*HD_, D_);
    gemm_mfma_split<<<dim3((NKV_*HD_)/128, M/128), 256, 0, stream>>>(xh, xl, wvh, wvl, wv_b, v, M, NKV_*HD_, D_);

    // 3) RoPE (+ scale into Q) and in-place interleaved hi/lo split
    rope_split_kernel<<<(M * NH_)  / 2, 256, 0, stream>>>(q, NH_,  0.08838834764831845f, 1);
    rope_split_kernel<<<(M * NKV_) / 2, 256, 0, stream>>>(k, NKV_, 1.0f, 1);
    rope_split_kernel<<<(M * NKV_) / 2, 256, 0, stream>>>(v, NKV_, 1.0f, 0);

    // 4) MFMA flash attention -> planar ctx hi/lo (x splits are dead now)
    flash_attn_mfma<<<dim3(S_/128, NH_, B_), 256, 0, stream>>>(
        (const ushort*)q, (const ushort*)k, (const ushort*)v, xh, xl);

    // 5) output projection (round-3-verified planar path)
    gemm_mfma_split<<<dim3(D_/128, M/128), 256, 0, stream>>>(xh, xl, woh, wol, nullptr, out, M, D_, D_);
}

// Round 7
// 1117.164 us; speedup vs baseline: 1.3864x; 1.3864x over previous
//
#include <hip/hip_runtime.h>
#include <cstdint>
#include <cstddef>

#define B_   4
#define S_   2048
#define D_   2048
#define NH_  16
#define NKV_ 4
#define HD_  128

typedef __attribute__((ext_vector_type(8))) short short8;
typedef __attribute__((ext_vector_type(4))) float f32x4;

// ---------------------------------------------------------------------------
// fp32 -> (bf16_hi, bf16_lo) split helpers (RNE)
// ---------------------------------------------------------------------------
__device__ __forceinline__ unsigned short f2bf(float f) {
    union { float f; unsigned u; } v{f};
    unsigned r = v.u + 0x7FFF + ((v.u >> 16) & 1);
    return (unsigned short)(r >> 16);
}
__device__ __forceinline__ float bf2f(unsigned short h) {
    union { unsigned u; float f; } v{(unsigned)h << 16};
    return v.f;
}
__device__ __forceinline__ void split1(float f, unsigned short& h, unsigned short& l) {
    h = f2bf(f);
    l = f2bf(f - bf2f(h));
}
// 8 packed u32 (hi|lo<<16) -> two bf16x8 fragments
__device__ __forceinline__ void unpack8(const unsigned* w, short8& hi, short8& lo) {
    unsigned h[4], l[4];
#pragma unroll
    for (int i = 0; i < 4; ++i) {
        h[i] = (w[2*i] & 0xFFFFu) | (w[2*i+1] << 16);
        l[i] = (w[2*i] >> 16) | (w[2*i+1] & 0xFFFF0000u);
    }
    hi = *(short8*)h; lo = *(short8*)l;
}

// src fp32 [n] -> hi/lo bf16 [n]. n must be a multiple of 1024.
__global__ __launch_bounds__(256) void split_bf16_k(
    const float* __restrict__ src, ushort* __restrict__ hi, ushort* __restrict__ lo)
{
    size_t i = ((size_t)blockIdx.x * 256 + threadIdx.x) * 4;
    float4 f = *(const float4*)&src[i];
    ushort4 h, l;
    split1(f.x, h.x, l.x); split1(f.y, h.y, l.y);
    split1(f.z, h.z, l.z); split1(f.w, h.w, l.w);
    *(ushort4*)&hi[i] = h;
    *(ushort4*)&lo[i] = l;
}

// ---------------------------------------------------------------------------
// Split-bf16 MFMA GEMM (round-3 verified form):
// C[M,N] = (Ah+Al)[M,K] @ (Bh+Bl)[N,K]^T + bias  (drops lo*lo)
// ---------------------------------------------------------------------------
__global__ __launch_bounds__(256) void gemm_mfma_split(
    const ushort* __restrict__ Ah, const ushort* __restrict__ Al,
    const ushort* __restrict__ Bh, const ushort* __restrict__ Bl,
    const float* __restrict__ bias, float* __restrict__ C,
    int M, int N, int K)
{
    __shared__ ushort sA[2][128 * 32];   // [0]=hi [1]=lo, row-major [128][32]
    __shared__ ushort sB[2][128 * 32];

    const int tid  = threadIdx.x;
    const int wave = tid >> 6;
    const int lane = tid & 63;
    const int bm = blockIdx.y * 128;
    const int bn = blockIdx.x * 128;
    const int wm = (wave & 1) * 64;
    const int wn = (wave >> 1) * 64;

    f32x4 acc[4][4];
#pragma unroll
    for (int mt = 0; mt < 4; ++mt)
#pragma unroll
        for (int nt = 0; nt < 4; ++nt) acc[mt][nt] = 0.f;

    const ushort* gbase = (wave == 0) ? Ah : (wave == 1) ? Al : (wave == 2) ? Bh : Bl;
    ushort* sbase = (wave == 0) ? sA[0] : (wave == 1) ? sA[1] : (wave == 2) ? sB[0] : sB[1];
    const int rb   = (wave < 2) ? bm : bn;
    const int lrow = lane >> 2;          // 0..15
    const int lcol = (lane & 3) * 8;     // element offset in k

    const int koff = (lane >> 4) * 8;
    const int rsel = lane & 15;

    for (int k0 = 0; k0 < K; k0 += 32) {
        __syncthreads();
        const ushort* g0 = gbase + (size_t)(rb + lrow) * K + k0 + lcol;
#pragma unroll
        for (int i = 0; i < 8; ++i) {
            __builtin_amdgcn_global_load_lds(
                (const __attribute__((address_space(1))) unsigned int*)(g0 + (size_t)i * 16 * K),
                (__attribute__((address_space(3))) unsigned int*)(sbase + i * 512),
                16, 0, 0);
        }
        __syncthreads();

        short8 a_h[4], a_l[4], b_h[4], b_l[4];
#pragma unroll
        for (int t = 0; t < 4; ++t) {
            a_h[t] = *(const short8*)&sA[0][(wm + t * 16 + rsel) * 32 + koff];
            a_l[t] = *(const short8*)&sA[1][(wm + t * 16 + rsel) * 32 + koff];
            b_h[t] = *(const short8*)&sB[0][(wn + t * 16 + rsel) * 32 + koff];
            b_l[t] = *(const short8*)&sB[1][(wn + t * 16 + rsel) * 32 + koff];
        }
#pragma unroll
        for (int mt = 0; mt < 4; ++mt)
#pragma unroll
            for (int nt = 0; nt < 4; ++nt) {
                acc[mt][nt] = __builtin_amdgcn_mfma_f32_16x16x32_bf16(a_h[mt], b_h[nt], acc[mt][nt], 0, 0, 0);
                acc[mt][nt] = __builtin_amdgcn_mfma_f32_16x16x32_bf16(a_h[mt], b_l[nt], acc[mt][nt], 0, 0, 0);
                acc[mt][nt] = __builtin_amdgcn_mfma_f32_16x16x32_bf16(a_l[mt], b_h[nt], acc[mt][nt], 0, 0, 0);
            }
    }

    const int crow0 = bm + wm + (lane >> 4) * 4;
    const int ccol0 = bn + wn + (lane & 15);
#pragma unroll
    for (int nt = 0; nt < 4; ++nt) {
        float bb = bias ? bias[ccol0 + nt * 16] : 0.f;
#pragma unroll
        for (int mt = 0; mt < 4; ++mt)
#pragma unroll
            for (int r = 0; r < 4; ++r)
                C[(size_t)(crow0 + mt * 16 + r) * N + ccol0 + nt * 16] = acc[mt][nt][r] + bb;
    }
}

// ---------------------------------------------------------------------------
// In-place RoPE (+scale) and fp32 -> interleaved hi/lo bf16 split.
// Row r of 128 fp32 becomes 128 hi ushorts | 128 lo ushorts (same 512 bytes).
// ---------------------------------------------------------------------------
__global__ __launch_bounds__(256) void rope_split_kernel(
    float* __restrict__ t, int H, float scale, int do_rope)
{
    const int tid = threadIdx.x;
    const int rid = blockIdx.x * 2 + (tid >> 7);
    const int d   = tid & 127;
    size_t fbase = (size_t)rid * 128;
    float val;
    if (do_rope) {
        const int s = (rid / H) & (S_ - 1);
        const int j = d & 63;
        float inv  = 1.0f / powf(1.0e6f, (float)j * (1.0f / 64.0f));
        float fr = (float)s * inv;
        float sn, cs; sincosf(fr, &sn, &cs);
        float x0 = t[fbase + d];
        float xp = t[fbase + (d ^ 64)];
        float rot = (d < 64) ? -xp : xp;
        val = fmaf(x0, cs, rot * sn) * scale;
    } else {
        val = t[fbase + d] * scale;
    }
    __syncthreads();               // all fp32 reads of these 2 rows done
    unsigned short h, l; split1(val, h, l);
    ushort* us = (ushort*)t;
    us[(size_t)rid * 256 + d]       = h;
    us[(size_t)rid * 256 + 128 + d] = l;
}

// ---------------------------------------------------------------------------
// MFMA causal flash attention, GQA, split-bf16 precision.
// Qsp: interleaved hi/lo Q rows [B,S,NH]x(128h|128l) (read-only here).
// Ksp/Vsp: interleaved hi/lo K/V rows [B,S,NKV]x(128h|128l).
// ctx_h/ctx_l: PLANAR outputs, [B*S][2048] ushorts, feature = h*128+d.
// Block: 4 waves x 32 q-rows per pass (BM=128); KV tile BN=32.
//
// Round 7: COMPLEMENTARY Q-TILE PAIRING. Causal cost of q-tile x is 4x+4
// KV-tiles; one block handles the pair {x, 15-x} sequentially, so every
// block does exactly 68 tile-units. Grid = 8x16x4 = 512 = 2 blocks/CU,
// all finishing simultaneously — kills the ~50% resident-wave idle the
// counters showed (R3/R1: occupancy = half of resident capacity at both
// 2-deep and 4-deep; heavy-first ordering + chunked dispatch piled the
// 64-tile blocks onto the same XCDs). Per-tile body is the verified R3
// structure (best measured: 528us).
//
// KV-row permutation trick: K rows staged at permuted row
// rho(kv) = ((kv&4)<<2) | ((kv>>3)<<2) | (kv&3) so QK^T's C-layout leaves
// each lane holding P at kv = quad*8 + mf*4 + r — exactly the contiguous
// 8-element k-slice its PV A-fragment needs. P never touches LDS.
//
// __launch_bounds__(256, 2): (256,4) forces VGPR 116->64 and spills (R1).
// ---------------------------------------------------------------------------
__global__ __launch_bounds__(256, 2) void flash_attn_mfma(
    const ushort* __restrict__ Qsp, const ushort* __restrict__ Ksp,
    const ushort* __restrict__ Vsp, ushort* __restrict__ ctx_h,
    ushort* __restrict__ ctx_l)
{
    __shared__ __align__(16) ushort Ks[32][280];      // hi at 0, lo at 144 (rows permuted)
    __shared__ __align__(16) unsigned Vt[128][36];    // [feat][kv] hi|lo<<16

    const int tid  = threadIdx.x;
    const int wave = tid >> 6;
    const int lane = tid & 63;
    const int l15  = lane & 15;
    const int quad = lane >> 4;
    const int h    = blockIdx.y;
    const int b    = blockIdx.z;
    const int kvh  = h >> 2;

    for (int pass = 0; pass < 2; ++pass) {
        const int xq  = pass ? (15 - (int)blockIdx.x) : (int)blockIdx.x;
        const int q0  = xq * 128;
        const int wq0 = q0 + wave * 32;

        // ---- Q fragments (B-operand) into registers: [nf][ks][plane] ----
        short8 qf[2][4][2];
#pragma unroll
        for (int nf = 0; nf < 2; ++nf)
#pragma unroll
            for (int ks = 0; ks < 4; ++ks) {
                size_t base = (((size_t)b * S_ + wq0 + nf * 16 + l15) * NH_ + h) * 256
                            + ks * 32 + quad * 8;
                qf[nf][ks][0] = *(const short8*)&Qsp[base];
                qf[nf][ks][1] = *(const short8*)&Qsp[base + 128];
            }

        f32x4 O[2][8];
#pragma unroll
        for (int mf = 0; mf < 2; ++mf)
#pragma unroll
            for (int nf = 0; nf < 8; ++nf) O[mf][nf] = 0.f;
        float m_[2] = {-3.0e38f, -3.0e38f};
        float l_[2] = {0.f, 0.f};

        const int ntiles = q0 / 32 + 4;
        for (int t = 0; t < ntiles; ++t) {
            const int k0 = t * 32;
            __syncthreads();                   // prev tile's (or pass's) LDS reads done

            // ---- stage K (32 rows x 256 ushorts), rows PERMUTED by rho() ----
#pragma unroll
            for (int i = 0; i < 4; ++i) {
                int c = tid + i * 256;         // 1024 chunks of 8 ushorts
                int row = c >> 5, seg = c & 31;
                int prow = ((row & 4) << 2) | ((row >> 3) << 2) | (row & 3);
                const ushort* src = Ksp + (((size_t)b * S_ + k0 + row) * NKV_ + kvh) * 256 + seg * 8;
                ushort* dst = &Ks[prow][seg * 8 + (seg >= 16 ? 16 : 0)];
                *(uint4*)dst = *(const uint4*)src;
            }
            // ---- stage V transposed+packed: Vt[feat][kv] = hi | lo<<16 ----
            {
                int row = tid & 31, fs = tid >> 5;
                const ushort* src = Vsp + (((size_t)b * S_ + k0 + row) * NKV_ + kvh) * 256 + fs * 16;
#pragma unroll
                for (int hf = 0; hf < 2; ++hf) {
                    uint4 hv = *(const uint4*)(src + hf * 8);
                    uint4 lv = *(const uint4*)(src + 128 + hf * 8);
                    const ushort* hp = (const ushort*)&hv;
                    const ushort* lp = (const ushort*)&lv;
#pragma unroll
                    for (int i = 0; i < 8; ++i)
                        Vt[fs * 16 + hf * 8 + i][row] = (unsigned)hp[i] | ((unsigned)lp[i] << 16);
                }
            }
            __syncthreads();

            // ---- S^T = K . Q^T  (rows kv-permuted, cols q) ----
            f32x4 st[2][2];                    // [nf(q)][mf(kv-tile)]
#pragma unroll
            for (int nf = 0; nf < 2; ++nf)
#pragma unroll
                for (int mf = 0; mf < 2; ++mf) st[nf][mf] = 0.f;
#pragma unroll
            for (int ks = 0; ks < 4; ++ks) {
                short8 kf_h[2], kf_l[2];
#pragma unroll
                for (int mf = 0; mf < 2; ++mf) {
                    kf_h[mf] = *(const short8*)&Ks[mf * 16 + l15][ks * 32 + quad * 8];
                    kf_l[mf] = *(const short8*)&Ks[mf * 16 + l15][144 + ks * 32 + quad * 8];
                }
#pragma unroll
                for (int nf = 0; nf < 2; ++nf)
#pragma unroll
                    for (int mf = 0; mf < 2; ++mf) {
                        st[nf][mf] = __builtin_amdgcn_mfma_f32_16x16x32_bf16(kf_h[mf], qf[nf][ks][0], st[nf][mf], 0, 0, 0);
                        st[nf][mf] = __builtin_amdgcn_mfma_f32_16x16x32_bf16(kf_h[mf], qf[nf][ks][1], st[nf][mf], 0, 0, 0);
                        st[nf][mf] = __builtin_amdgcn_mfma_f32_16x16x32_bf16(kf_l[mf], qf[nf][ks][0], st[nf][mf], 0, 0, 0);
                    }
            }

            // ---- causal mask (actual kv = k0 + quad*8 + mf*4 + r) ----
            if (k0 + 31 > wq0) {
#pragma unroll
                for (int nf = 0; nf < 2; ++nf)
#pragma unroll
                    for (int mf = 0; mf < 2; ++mf)
#pragma unroll
                        for (int r = 0; r < 4; ++r) {
                            int kg = k0 + quad * 8 + mf * 4 + r;
                            int qg = wq0 + nf * 16 + l15;
                            if (kg > qg) st[nf][mf][r] = -3.0e38f;
                        }
            }

            // ---- online softmax (per q column; reduce in-lane + across quads) ----
            float alp[2];
#pragma unroll
            for (int nf = 0; nf < 2; ++nf) {
                float rm = -3.0e38f;
#pragma unroll
                for (int mf = 0; mf < 2; ++mf)
#pragma unroll
                    for (int r = 0; r < 4; ++r) rm = fmaxf(rm, st[nf][mf][r]);
                rm = fmaxf(rm, __shfl_xor(rm, 16));
                rm = fmaxf(rm, __shfl_xor(rm, 32));
                float mn = fmaxf(m_[nf], rm);
                float a  = __expf(m_[nf] - mn);
                float rs = 0.f;
#pragma unroll
                for (int mf = 0; mf < 2; ++mf)
#pragma unroll
                    for (int r = 0; r < 4; ++r) {
                        float p = __expf(st[nf][mf][r] - mn);
                        st[nf][mf][r] = p;
                        rs += p;
                    }
                rs += __shfl_xor(rs, 16);
                rs += __shfl_xor(rs, 32);
                l_[nf] = l_[nf] * a + rs;
                m_[nf] = mn;
                alp[nf] = a;
            }

            // ---- rescale O (alpha fetched from owner lane of each q row) ----
#pragma unroll
            for (int omf = 0; omf < 2; ++omf)
#pragma unroll
                for (int r = 0; r < 4; ++r) {
                    float av = __shfl(alp[omf], (lane & 48) | (quad * 4 + r));
#pragma unroll
                    for (int nf = 0; nf < 8; ++nf) O[omf][nf][r] *= av;
                }

            // ---- P stays in registers: lane already holds kv = quad*8+0..7 ----
            short8 ph[2], pl[2];
#pragma unroll
            for (int omf = 0; omf < 2; ++omf) {
                unsigned hu[4], lu[4];
#pragma unroll
                for (int mf = 0; mf < 2; ++mf)
#pragma unroll
                    for (int pr = 0; pr < 2; ++pr) {
                        unsigned short ah, al, bh, bl;
                        split1(st[omf][mf][pr * 2],     ah, al);
                        split1(st[omf][mf][pr * 2 + 1], bh, bl);
                        hu[mf * 2 + pr] = (unsigned)ah | ((unsigned)bh << 16);
                        lu[mf * 2 + pr] = (unsigned)al | ((unsigned)bl << 16);
                    }
                ph[omf] = *(short8*)hu;
                pl[omf] = *(short8*)lu;
            }

            // ---- O += P . V ----
#pragma unroll
            for (int vnf = 0; vnf < 8; ++vnf) {
                const unsigned* vw = &Vt[vnf * 16 + l15][quad * 8];
                unsigned w[8];
                *(uint4*)w       = *(const uint4*)vw;
                *(uint4*)(w + 4) = *(const uint4*)(vw + 4);
                short8 vh, vl;
                unpack8(w, vh, vl);
#pragma unroll
                for (int omf = 0; omf < 2; ++omf) {
                    O[omf][vnf] = __builtin_amdgcn_mfma_f32_16x16x32_bf16(ph[omf], vh, O[omf][vnf], 0, 0, 0);
                    O[omf][vnf] = __builtin_amdgcn_mfma_f32_16x16x32_bf16(ph[omf], vl, O[omf][vnf], 0, 0, 0);
                    O[omf][vnf] = __builtin_amdgcn_mfma_f32_16x16x32_bf16(pl[omf], vh, O[omf][vnf], 0, 0, 0);
                }
            }
        }

        // ---- epilogue: normalize, split, store planar ctx ----
        float li[2] = {1.f / l_[0], 1.f / l_[1]};
#pragma unroll
        for (int omf = 0; omf < 2; ++omf)
#pragma unroll
            for (int r = 0; r < 4; ++r) {
                float il = __shfl(li[omf], (lane & 48) | (quad * 4 + r));
                int qrow = wq0 + omf * 16 + quad * 4 + r;
                size_t rowb = ((size_t)b * S_ + qrow) * (size_t)D_ + h * HD_;
#pragma unroll
                for (int nf = 0; nf < 8; ++nf) {
                    float val = O[omf][nf][r] * il;
                    unsigned short hh, ll; split1(val, hh, ll);
                    int feat = nf * 16 + l15;
                    ctx_h[rowb + feat] = hh;
                    ctx_l[rowb + feat] = ll;
                }
            }
    }
}

// ---------------------------------------------------------------------------
extern "C" void kernel_launch(void* const* d_in, const int* in_sizes, int n_in,
                              void* d_out, int out_size, void* d_ws, size_t ws_size,
                              hipStream_t stream)
{
    const float* x    = (const float*)d_in[0];
    const float* wq_w = (const float*)d_in[1];
    const float* wq_b = (const float*)d_in[2];
    const float* wk_w = (const float*)d_in[3];
    const float* wk_b = (const float*)d_in[4];
    const float* wv_w = (const float*)d_in[5];
    const float* wv_b = (const float*)d_in[6];
    const float* wo_w = (const float*)d_in[7];
    float* out = (float*)d_out;

    const int M = B_ * S_;                        // 8192
    const size_t NX   = (size_t)M * D_;           // 16,777,216
    const size_t NKVE = (size_t)M * NKV_ * HD_;   // 4,194,304
    const size_t NWQ  = (size_t)D_ * D_;
    const size_t NWK  = (size_t)(NKV_ * HD_) * D_;

    // workspace layout
    float*  q   = (float*)d_ws;          // becomes interleaved split Q
    float*  k   = q + NX;                // becomes interleaved split K
    float*  v   = k + NKVE;              // becomes interleaved split V
    ushort* xh  = (ushort*)(v + NKVE);   // x hi split; later ctx_h (planar)
    ushort* xl  = xh + NX;               // x lo split; later ctx_l (planar)
    ushort* wqh = xl + NX;
    ushort* wql = wqh + NWQ;
    ushort* wkh = wql + NWQ;
    ushort* wkl = wkh + NWK;
    ushort* wvh = wkl + NWK;
    ushort* wvl = wvh + NWK;
    ushort* woh = wvl + NWK;
    ushort* wol = woh + NWQ;

    // 1) fp32 -> bf16 hi/lo splits
    split_bf16_k<<<NX  / 1024, 256, 0, stream>>>(x,    xh,  xl);
    split_bf16_k<<<NWQ / 1024, 256, 0, stream>>>(wq_w, wqh, wql);
    split_bf16_k<<<NWK / 1024, 256, 0, stream>>>(wk_w, wkh, wkl);
    split_bf16_k<<<NWK / 1024, 256, 0, stream>>>(wv_w, wvh, wvl);
    split_bf16_k<<<NWQ / 1024, 256, 0, stream>>>(wo_w, woh, wol);

    // 2) QKV projections (fp32 outputs)
    gemm_mfma_split<<<dim3(D_/128,         M/128), 256, 0, stream>>>(xh, xl, wqh, wql, wq_b, q, M, D_,       D_);
    gemm_mfma_split<<<dim3((NKV_*HD_)/128, M/128), 256, 0, stream>>>(xh, xl, wkh, wkl, wk_b, k, M, NKV_*HD_, D_);
    gemm_mfma_split<<<dim3((NKV_*HD_)/128, M/128), 256, 0, stream>>>(xh, xl, wvh, wvl, wv_b, v, M, NKV_*HD_, D_);

    // 3) RoPE (+ scale into Q) and in-place interleaved hi/lo split
    rope_split_kernel<<<(M * NH_)  / 2, 256, 0, stream>>>(q, NH_,  0.08838834764831845f, 1);
    rope_split_kernel<<<(M * NKV_) / 2, 256, 0, stream>>>(k, NKV_, 1.0f, 1);
    rope_split_kernel<<<(M * NKV_) / 2, 256, 0, stream>>>(v, NKV_, 1.0f, 0);

    // 4) MFMA flash attention -> planar ctx hi/lo (x splits are dead now)
    //    paired q-tiles: gridDim.x = S/256 = 8, each block does {x, 15-x}
    flash_attn_mfma<<<dim3(S_/256, NH_, B_), 256, 0, stream>>>(
        (const ushort*)q, (const ushort*)k, (const ushort*)v, xh, xl);

    // 5) output projection (round-3-verified planar path)
    gemm_mfma_split<<<dim3(D_/128, M/128), 256, 0, stream>>>(xh, xl, woh, wol, nullptr, out, M, D_, D_);
}